// Round 1
// baseline (2768.614 us; speedup 1.0000x reference)
//
#include <hip/hip_runtime.h>
#include <hip/hip_bf16.h>

#define N_TRAIN 200000
#define DIMS    64
#define NQ      1024
#define KSEL    32
#define NCLS    10

#define QB      32      // queries per filter block
#define NBLK    64      // n-chunks
#define CHUNK   3125    // N_TRAIN / NBLK
#define SUB     128     // rows staged in LDS per iteration
#define CMAX    64      // candidate buffer per (query, nblk)
#define SAMPLES 4096
#define SSTRIDE 48

__device__ __forceinline__ unsigned fmap(float f) {
    unsigned u = __float_as_uint(f);
    return u ^ ((u >> 31) ? 0xFFFFFFFFu : 0x80000000u);
}
__device__ __forceinline__ float funmap(unsigned m) {
    unsigned u = m ^ ((m >> 31) ? 0x80000000u : 0xFFFFFFFFu);
    return __uint_as_float(u);
}

// ---------------------------------------------------------------- x2 = ||x||^2
__global__ __launch_bounds__(256) void k_x2(const float* __restrict__ X,
                                            float* __restrict__ x2) {
    int T = blockIdx.x * 256 + threadIdx.x;      // 16 threads per row
    int row = T >> 4;
    int l16 = T & 15;
    float4 v = ((const float4*)X)[(long)row * 16 + l16];
    float p = v.x * v.x + v.y * v.y + v.z * v.z + v.w * v.w;
    p += __shfl_xor(p, 1);
    p += __shfl_xor(p, 2);
    p += __shfl_xor(p, 4);
    p += __shfl_xor(p, 8);
    if (l16 == 0) x2[row] = p;
}

// ------------------------------------------- per-query threshold via sampling
__global__ __launch_bounds__(256) void k_thresh(const float* __restrict__ Qm,
                                                const float* __restrict__ X,
                                                const float* __restrict__ x2,
                                                float* __restrict__ tq) {
    int q = blockIdx.x;
    int tid = threadIdx.x;
    __shared__ float4 qv4[16];
    __shared__ int cnt;
    if (tid < 16) qv4[tid] = ((const float4*)(Qm + (long)q * DIMS))[tid];
    __syncthreads();

    float4 qf[16];
#pragma unroll
    for (int k = 0; k < 16; k++) qf[k] = qv4[k];

    unsigned mk[16];
#pragma unroll
    for (int i = 0; i < 16; i++) {
        int s = tid + 256 * i;           // 0..4095
        int row = s * SSTRIDE;           // < 200000
        const float4* xr = (const float4*)(X + (long)row * DIMS);
        float dot = 0.f;
#pragma unroll
        for (int k = 0; k < 16; k++) {
            float4 xv = xr[k];
            dot += qf[k].x * xv.x + qf[k].y * xv.y + qf[k].z * xv.z + qf[k].w * xv.w;
        }
        float key = x2[row] - 2.f * dot;
        mk[i] = fmap(key);
    }

    // integer bisection for exact 32nd-smallest mapped key among samples
    unsigned lo = 0u, hi = 0xFFFFFFFFu;
    for (int it = 0; it < 32; ++it) {
        if (tid == 0) cnt = 0;
        __syncthreads();
        unsigned mid = lo + ((hi - lo) >> 1);
        int c = 0;
#pragma unroll
        for (int i = 0; i < 16; i++) c += (mk[i] <= mid) ? 1 : 0;
        atomicAdd(&cnt, c);
        __syncthreads();
        int total = cnt;
        __syncthreads();
        if (total >= KSEL) hi = mid; else lo = mid + 1;
    }
    if (tid == 0) tq[q] = funmap(hi) + 0.01f;   // margin >> fp reorder noise
}

// ------------------------------------------------ filter pass (the big GEMM)
__global__ __launch_bounds__(256) void k_filter(const float* __restrict__ Qm,
                                                const float* __restrict__ X,
                                                const float* __restrict__ x2,
                                                const float* __restrict__ tq,
                                                int* __restrict__ cnt_g,
                                                uint2* __restrict__ cand_g) {
    int bid = blockIdx.x;
    int qt = bid & (NQ / QB - 1);   // query-tile fastest -> same n-chunk co-resident
    int nb = bid >> 5;
    int tid = threadIdx.x;

    __shared__ float4 xs4[SUB * 16];     // swizzled: slot = row*16 + (k4 ^ (row&15))
    __shared__ float x2s[SUB];
    __shared__ float4 qs4[QB * 16];
    __shared__ float tqs[QB];
    __shared__ int ccnt[QB];
    __shared__ uint2 cbuf[QB * CMAX];

    for (int c = tid; c < QB * 16; c += 256)
        qs4[c] = ((const float4*)(Qm + (long)qt * QB * DIMS))[c];
    if (tid < QB) {
        tqs[tid] = tq[qt * QB + tid];
        ccnt[tid] = 0;
    }

    int tq_ = tid >> 5;        // 0..7
    int tn_ = tid & 31;        // 0..31
    int q0 = tq_ * 4;
    int rs0 = tn_ & 15;

    int rowBeg = nb * CHUNK;
    int rowEnd = rowBeg + CHUNK;

    for (int sb = rowBeg; sb < rowEnd; sb += SUB) {
        int nvalid = min(SUB, rowEnd - sb);
        __syncthreads();   // protect LDS reuse (also covers initial q staging)
#pragma unroll
        for (int m = 0; m < 8; m++) {
            int c = tid + 256 * m;
            int row = c >> 4, k4 = c & 15;
            float4 v = make_float4(0.f, 0.f, 0.f, 0.f);
            if (row < nvalid) v = ((const float4*)X)[(long)(sb + row) * 16 + k4];
            xs4[row * 16 + (k4 ^ (row & 15))] = v;
        }
        if (tid < SUB) x2s[tid] = (tid < nvalid) ? x2[sb + tid] : 1e30f;
        __syncthreads();

        float acc[4][4];
#pragma unroll
        for (int i = 0; i < 4; i++)
#pragma unroll
            for (int j = 0; j < 4; j++) acc[i][j] = 0.f;

#pragma unroll
        for (int k4 = 0; k4 < 16; k4++) {
            float4 xv[4], qv[4];
#pragma unroll
            for (int j = 0; j < 4; j++)
                xv[j] = xs4[(tn_ + 32 * j) * 16 + (k4 ^ rs0)];
#pragma unroll
            for (int i = 0; i < 4; i++)
                qv[i] = qs4[(q0 + i) * 16 + k4];
#pragma unroll
            for (int i = 0; i < 4; i++)
#pragma unroll
                for (int j = 0; j < 4; j++)
                    acc[i][j] += qv[i].x * xv[j].x + qv[i].y * xv[j].y +
                                 qv[i].z * xv[j].z + qv[i].w * xv[j].w;
        }

        // epilogue: threshold test + rare append
#pragma unroll
        for (int j = 0; j < 4; j++) {
            int row = tn_ + 32 * j;
            float xx = x2s[row];
            int gidx = sb + row;
#pragma unroll
            for (int i = 0; i < 4; i++) {
                float key = xx - 2.f * acc[i][j];
                if (key <= tqs[q0 + i]) {
                    int qq = q0 + i;
                    int slot = atomicAdd(&ccnt[qq], 1);
                    if (slot < CMAX)
                        cbuf[qq * CMAX + slot] =
                            make_uint2(__float_as_uint(key), (unsigned)gidx);
                }
            }
        }
    }

    __syncthreads();
    if (tid < QB) cnt_g[(qt * QB + tid) * NBLK + nb] = min(ccnt[tid], CMAX);
    for (int e = tid; e < QB * CMAX; e += 256) {
        int qq = e >> 6, s = e & 63;
        if (s < min(ccnt[qq], CMAX))
            cand_g[((long)(qt * QB + qq) * NBLK + nb) * CMAX + s] = cbuf[e];
    }
}

// -------------------------------------------------- merge + vote + argmax
#define TOTSLOT (NBLK * CMAX)   // 4096
__global__ __launch_bounds__(256) void k_merge(const float* __restrict__ Qm,
                                               const int* __restrict__ labels,
                                               const int* __restrict__ cnt_g,
                                               const uint2* __restrict__ cand_g,
                                               int* __restrict__ out) {
    int q = blockIdx.x;
    int tid = threadIdx.x;
    __shared__ float keyL[TOTSLOT];
    __shared__ int idxL[TOTSLOT];
    __shared__ int labL[TOTSLOT];
    __shared__ int cnts[NBLK];
    __shared__ float q2s;
    __shared__ float redK[4];
    __shared__ int redI[4];
    __shared__ int redG[4];

    if (tid < NBLK) cnts[tid] = cnt_g[q * NBLK + tid];
    if (tid < 64) {
        float v = Qm[(long)q * DIMS + tid];
        float p = v * v;
        p += __shfl_xor(p, 1);
        p += __shfl_xor(p, 2);
        p += __shfl_xor(p, 4);
        p += __shfl_xor(p, 8);
        p += __shfl_xor(p, 16);
        p += __shfl_xor(p, 32);
        if (tid == 0) q2s = p;
    }
    __syncthreads();

#pragma unroll
    for (int m = 0; m < 16; m++) {
        int g = tid + 256 * m;
        int b = g >> 6, s = g & 63;
        float k = 1e30f;
        int ix = 0x7FFFFFFF, lb = 0;
        if (s < cnts[b]) {
            uint2 e = cand_g[((long)q * NBLK + b) * CMAX + s];
            k = __uint_as_float(e.x);
            ix = (int)e.y;
            lb = labels[ix];
        }
        keyL[g] = k;
        idxL[g] = ix;
        labL[g] = lb;
    }
    __syncthreads();

    float votes[NCLS] = {0.f, 0.f, 0.f, 0.f, 0.f, 0.f, 0.f, 0.f, 0.f, 0.f};
    for (int it = 0; it < KSEL; ++it) {
        float bk = 1e30f;
        int bi = 0x7FFFFFFF, bg = -1;
#pragma unroll
        for (int m = 0; m < 16; m++) {
            int g = tid + 256 * m;
            float k = keyL[g];
            int ix = idxL[g];
            if (k < bk || (k == bk && ix < bi)) { bk = k; bi = ix; bg = g; }
        }
#pragma unroll
        for (int d = 32; d > 0; d >>= 1) {
            float ok = __shfl_down(bk, d);
            int oi = __shfl_down(bi, d);
            int og = __shfl_down(bg, d);
            if (ok < bk || (ok == bk && oi < bi)) { bk = ok; bi = oi; bg = og; }
        }
        int w = tid >> 6;
        if ((tid & 63) == 0) { redK[w] = bk; redI[w] = bi; redG[w] = bg; }
        __syncthreads();
        if (tid == 0) {
#pragma unroll
            for (int w2 = 1; w2 < 4; w2++) {
                if (redK[w2] < bk || (redK[w2] == bk && redI[w2] < bi)) {
                    bk = redK[w2]; bi = redI[w2]; bg = redG[w2];
                }
            }
            if (bg >= 0) {
                keyL[bg] = 1e30f;             // consume winner
                float dist = q2s + bk;        // sim = q2 + x2 - 2 q.x
                if (dist < 0.f) dist = 0.f;   // maximum(sim, 0)
                if (dist == 0.f) dist = 0.1f; // where(sim==0, 0.1)
                float wgt = 1.f / dist;
                int lb = labL[bg];
#pragma unroll
                for (int c = 0; c < NCLS; c++) votes[c] += (lb == c) ? wgt : 0.f;
            }
        }
        __syncthreads();
    }
    if (tid == 0) {
        float bv = votes[0];
        int bc = 0;
#pragma unroll
        for (int c = 1; c < NCLS; c++)
            if (votes[c] > bv) { bv = votes[c]; bc = c; }
        out[q] = bc;
    }
}

extern "C" void kernel_launch(void* const* d_in, const int* in_sizes, int n_in,
                              void* d_out, int out_size, void* d_ws, size_t ws_size,
                              hipStream_t stream) {
    const float* Qm = (const float*)d_in[0];
    const float* X = (const float*)d_in[1];
    const int* labels = (const int*)d_in[2];
    char* ws = (char*)d_ws;
    // ws layout (total ~34.6 MB):
    float* x2 = (float*)ws;                        //   800000 B
    float* tqv = (float*)(ws + 800000);            //     4096 B
    int* cnt_g = (int*)(ws + 804096);              //   262144 B
    uint2* cand_g = (uint2*)(ws + 1066240);        // 33554432 B
    int* out = (int*)d_out;

    k_x2<<<12500, 256, 0, stream>>>(X, x2);
    k_thresh<<<NQ, 256, 0, stream>>>(Qm, X, x2, tqv);
    k_filter<<<(NQ / QB) * NBLK, 256, 0, stream>>>(Qm, X, x2, tqv, cnt_g, cand_g);
    k_merge<<<NQ, 256, 0, stream>>>(Qm, labels, cnt_g, cand_g, out);
}

// Round 3
// 1407.874 us; speedup vs baseline: 1.9665x; 1.9665x over previous
//
#include <hip/hip_runtime.h>
#include <hip/hip_bf16.h>

#define N_TRAIN 200000
#define DIMS    64
#define NQ      1024
#define KSEL    32
#define NCLS    10

#define QB      128     // queries per gemm block (8 query tiles of 16)
#define NQT     8       // NQ/QB
#define CHUNKS  64      // n-chunks for filter
#define CHROWS  3125    // N_TRAIN / CHUNKS
#define CMAX    96      // candidate cap per (query, chunk)
#define MAXC    4096    // merge candidate cap per query
#define SAMPLES 8192    // threshold sample rows (rows 0..8191)
#define SCH     1024    // sample rows per MODE1 block

typedef float f32x4 __attribute__((ext_vector_type(4)));
typedef short bf16x8 __attribute__((ext_vector_type(8)));

__device__ __forceinline__ unsigned fmap(float f) {
    unsigned u = __float_as_uint(f);
    return u ^ ((u >> 31) ? 0xFFFFFFFFu : 0x80000000u);
}
__device__ __forceinline__ float funmap(unsigned m) {
    unsigned u = m ^ ((m >> 31) ? 0x80000000u : 0xFFFFFFFFu);
    return __uint_as_float(u);
}
__device__ __forceinline__ unsigned short f2bf(float f) {   // RNE f32->bf16 bits
    unsigned u = __float_as_uint(f);
    unsigned r = u + 0x7FFFu + ((u >> 16) & 1u);
    return (unsigned short)(r >> 16);
}
__device__ __forceinline__ bf16x8 pack8(float4 a, float4 b) {
    bf16x8 r;
    r[0] = (short)f2bf(a.x); r[1] = (short)f2bf(a.y);
    r[2] = (short)f2bf(a.z); r[3] = (short)f2bf(a.w);
    r[4] = (short)f2bf(b.x); r[5] = (short)f2bf(b.y);
    r[6] = (short)f2bf(b.z); r[7] = (short)f2bf(b.w);
    return r;
}

// ------------------------------------------------ x2 = ||x||^2 + global max
__global__ __launch_bounds__(256) void k_x2(const float* __restrict__ X,
                                            float* __restrict__ x2,
                                            int* __restrict__ x2max) {
    int T = blockIdx.x * 256 + threadIdx.x;      // 16 threads per row
    int row = T >> 4;
    int l16 = T & 15;
    float4 v = ((const float4*)X)[(long)row * 16 + l16];
    float p = v.x * v.x + v.y * v.y + v.z * v.z + v.w * v.w;
    p += __shfl_xor(p, 1);
    p += __shfl_xor(p, 2);
    p += __shfl_xor(p, 4);
    p += __shfl_xor(p, 8);    // all lanes in 16-group hold the row sum
    if (l16 == 0) x2[row] = p;
    float m = p;
    m = fmaxf(m, __shfl_xor(m, 16));
    m = fmaxf(m, __shfl_xor(m, 32));
    if ((threadIdx.x & 63) == 0) atomicMax(x2max, __float_as_int(m));
}

// ------------------------------------------------ MFMA distance pass
// MODE 0: filter full dataset against widened thresholds, append candidates
// MODE 1: write u16-mapped keys for sample rows [cb*SCH, cb*SCH+SCH)
template<int MODE>
__global__ __launch_bounds__(256, 2) void k_gemm(
    const float* __restrict__ Xf,
    const float* __restrict__ Qm, const float* __restrict__ x2,
    const float* __restrict__ tqw, int* __restrict__ cnt_g,
    unsigned* __restrict__ cand, unsigned short* __restrict__ keys) {
    int bid = blockIdx.x;
    int qt = bid & (NQT - 1);
    int cb = bid >> 3;
    int r0 = cb * (MODE ? SCH : CHROWS);
    int rcnt = MODE ? SCH : CHROWS;

    int tid = threadIdx.x;
    int lane = tid & 63;
    int w = tid >> 6;          // wave 0..3
    int lr = lane & 15;        // A-row / B-col within tile
    int lk = lane >> 4;        // k-quarter 0..3

    __shared__ short xs[256 * 64];   // 32 KB, 16B chunks XOR-swizzled by row&7
    __shared__ float x2s[256];
    __shared__ float tqh[QB];

    if (MODE == 0 && tid < QB) tqh[tid] = 0.5f * tqw[(qt << 7) + tid];
    __syncthreads();

    float htqmax[8];
    if (MODE == 0) {
#pragma unroll
        for (int qi = 0; qi < 8; qi++) {
            int b = (qi << 4) + (lk << 2);
            htqmax[qi] = fmaxf(fmaxf(tqh[b], tqh[b + 1]), fmaxf(tqh[b + 2], tqh[b + 3]));
        }
    }

    // A fragments: lane holds Q[qt*128+qi*16+lr][kh*32 + lk*8 + j], j=0..7
    bf16x8 afr[8][2];
#pragma unroll
    for (int qi = 0; qi < 8; qi++) {
        int qrow = (qt << 7) + (qi << 4) + lr;
        const float4* qp0 = (const float4*)(Qm + (long)qrow * 64 + lk * 8);
        const float4* qp1 = (const float4*)(Qm + (long)qrow * 64 + 32 + lk * 8);
        afr[qi][0] = pack8(qp0[0], qp0[1]);
        afr[qi][1] = pack8(qp1[0], qp1[1]);
    }

    for (int sb = 0; sb < rcnt; sb += 256) {
        int nv = min(256, rcnt - sb);
        __syncthreads();
#pragma unroll
        for (int m = 0; m < 8; m++) {
            int c = tid + 256 * m;              // 2048 16B chunks
            int row = c >> 3, ch = c & 7;
            bf16x8 v = {0, 0, 0, 0, 0, 0, 0, 0};
            if (row < nv) {
                long gr = (long)(r0 + sb + row);
                const float4* xp = (const float4*)(Xf + gr * 64 + ch * 8);
                v = pack8(xp[0], xp[1]);
            }
            *(bf16x8*)(xs + row * 64 + ((ch ^ (row & 7)) * 8)) = v;
        }
        x2s[tid] = (tid < nv) ? x2[r0 + sb + tid] : 1e30f;
        __syncthreads();

#pragma unroll
        for (int j = 0; j < 4; j++) {
            int nr = (w << 6) + (j << 4) + lr;   // local train row
            int sw = nr & 7;
            bf16x8 b0 = *(const bf16x8*)(xs + nr * 64 + ((lk ^ sw) * 8));
            bf16x8 b1 = *(const bf16x8*)(xs + nr * 64 + (((4 + lk) ^ sw) * 8));
            float x2v = x2s[nr];
            float hx = 0.5f * x2v;
#pragma unroll
            for (int qi = 0; qi < 8; qi++) {
                f32x4 acc = {0.f, 0.f, 0.f, 0.f};
                acc = __builtin_amdgcn_mfma_f32_16x16x32_bf16(afr[qi][0], b0, acc, 0, 0, 0);
                acc = __builtin_amdgcn_mfma_f32_16x16x32_bf16(afr[qi][1], b1, acc, 0, 0, 0);
                if (MODE == 1) {
                    int sg = r0 + sb + nr;
#pragma unroll
                    for (int r = 0; r < 4; r++) {
                        float key = x2v - 2.f * acc[r];
                        int qg = (qt << 7) + (qi << 4) + (lk << 2) + r;
                        keys[(long)qg * SAMPLES + sg] = (unsigned short)(fmap(key) >> 16);
                    }
                } else {
                    float mx = fmaxf(fmaxf(acc[0], acc[1]), fmaxf(acc[2], acc[3]));
                    if (mx + htqmax[qi] >= hx) {       // sound quick reject
#pragma unroll
                        for (int r = 0; r < 4; r++) {
                            if (acc[r] + tqh[(qi << 4) + (lk << 2) + r] >= hx) {
                                int qg = (qt << 7) + (qi << 4) + (lk << 2) + r;
                                int ng = r0 + sb + nr;
                                int slot = atomicAdd(&cnt_g[qg * CHUNKS + cb], 1);
                                if (slot < CMAX)
                                    cand[((long)qg * CHUNKS + cb) * CMAX + slot] = (unsigned)ng;
                            }
                        }
                    }
                }
            }
        }
    }
}

// ------------------------------------------------ 32nd-smallest sample key -> threshold
__global__ __launch_bounds__(256) void k_sel(const unsigned short* __restrict__ keys,
                                             const float* __restrict__ Qm,
                                             const int* __restrict__ x2max_i,
                                             float* __restrict__ tqw,
                                             float* __restrict__ q2g) {
    int q = blockIdx.x, tid = threadIdx.x;
    unsigned short mk[32];
#pragma unroll
    for (int m = 0; m < 32; m++) mk[m] = keys[(long)q * SAMPLES + tid + 256 * m];
    __shared__ float q2s_;
    __shared__ int cnt;
    if (tid < 64) {
        float v = Qm[(long)q * 64 + tid];
        float p = v * v;
#pragma unroll
        for (int d = 1; d < 64; d <<= 1) p += __shfl_xor(p, d);
        if (tid == 0) q2s_ = p;
    }
    unsigned lo = 0, hi = 65535;
    for (int it = 0; it < 16; ++it) {
        __syncthreads();
        if (tid == 0) cnt = 0;
        __syncthreads();
        unsigned mid = (lo + hi) >> 1;
        int c = 0;
#pragma unroll
        for (int m = 0; m < 32; m++) c += (mk[m] <= mid) ? 1 : 0;
#pragma unroll
        for (int d = 1; d < 64; d <<= 1) c += __shfl_xor(c, d);
        if ((tid & 63) == 0) atomicAdd(&cnt, c);
        __syncthreads();
        if (cnt >= KSEL) hi = mid; else lo = mid + 1;
    }
    if (tid == 0) {
        unsigned vv = hi + 2u; if (vv > 65535u) vv = 65535u;
        float t = funmap(vv << 16);
        float x2m = __int_as_float(*x2max_i);
        float q2 = q2s_;
        // widen: 2 * bf16 dot-error bound (2^-6.99 * ||q|| * ||x||max each) + margin
        tqw[q] = t + 0.0314f * sqrtf(q2 * x2m) + 0.2f;
        q2g[q] = q2;
    }
}

// ------------------------------------------------ exact re-rank + vote + argmax
__global__ __launch_bounds__(256) void k_merge(const float* __restrict__ Qm,
                                               const float* __restrict__ X,
                                               const float* __restrict__ x2,
                                               const int* __restrict__ labels,
                                               const int* __restrict__ cnt_g,
                                               const unsigned* __restrict__ cand,
                                               const float* __restrict__ q2g,
                                               int* __restrict__ out) {
    int q = blockIdx.x, tid = threadIdx.x;
    __shared__ int idxL[MAXC];
    __shared__ float keyL[MAXC];
    __shared__ int labL[MAXC];
    __shared__ float qs[64];
    __shared__ int cnts[CHUNKS];
    __shared__ int tot;
    __shared__ float redK[4];
    __shared__ int redI[4];
    __shared__ int redG[4];

    if (tid == 0) tot = 0;
    if (tid < CHUNKS) cnts[tid] = min(cnt_g[q * CHUNKS + tid], CMAX);
    if (tid < 64) qs[tid] = Qm[(long)q * 64 + tid];
    for (int i = tid; i < MAXC; i += 256) { keyL[i] = 1e30f; idxL[i] = 0x7FFFFFFF; labL[i] = 0; }
    __syncthreads();

#pragma unroll
    for (int m = 0; m < 24; m++) {           // 64 chunks * 96 slots = 6144
        int g = tid + 256 * m;
        int c = g / CMAX, s = g - c * CMAX;
        if (s < cnts[c]) {
            int p = atomicAdd(&tot, 1);
            if (p < MAXC) idxL[p] = (int)cand[((long)q * CHUNKS + c) * CMAX + s];
        }
    }
    __syncthreads();
    int T = min(tot, MAXC);
    for (int i = tid; i < T; i += 256) {     // exact fp32 keys for candidates
        int ix = idxL[i];
        const float4* xr = (const float4*)(X + (long)ix * 64);
        const float4* qr = (const float4*)qs;
        float dot = 0.f;
#pragma unroll
        for (int k4 = 0; k4 < 16; k4++) {
            float4 xv = xr[k4];
            float4 qv = qr[k4];
            dot += qv.x * xv.x + qv.y * xv.y + qv.z * xv.z + qv.w * xv.w;
        }
        keyL[i] = x2[ix] - 2.f * dot;
        labL[i] = labels[ix];
    }
    __syncthreads();

    float q2v = q2g[q];
    float votes[NCLS] = {0.f, 0.f, 0.f, 0.f, 0.f, 0.f, 0.f, 0.f, 0.f, 0.f};
    for (int it = 0; it < KSEL; ++it) {
        float bk = 1e30f;
        int bi = 0x7FFFFFFF, bg = -1;
#pragma unroll
        for (int m = 0; m < 16; m++) {
            int g = tid + 256 * m;
            float k = keyL[g];
            int ix = idxL[g];
            if (k < bk || (k == bk && ix < bi)) { bk = k; bi = ix; bg = g; }
        }
#pragma unroll
        for (int d = 32; d > 0; d >>= 1) {
            float ok = __shfl_down(bk, d);
            int oi = __shfl_down(bi, d);
            int og = __shfl_down(bg, d);
            if (ok < bk || (ok == bk && oi < bi)) { bk = ok; bi = oi; bg = og; }
        }
        int wv = tid >> 6;
        if ((tid & 63) == 0) { redK[wv] = bk; redI[wv] = bi; redG[wv] = bg; }
        __syncthreads();
        if (tid == 0) {
#pragma unroll
            for (int w2 = 1; w2 < 4; w2++) {
                if (redK[w2] < bk || (redK[w2] == bk && redI[w2] < bi)) {
                    bk = redK[w2]; bi = redI[w2]; bg = redG[w2];
                }
            }
            if (bg >= 0) {
                keyL[bg] = 1e30f;             // consume winner
                float dist = q2v + bk;        // sim = q2 + x2 - 2 q.x
                if (dist < 0.f) dist = 0.f;   // maximum(sim, 0)
                if (dist == 0.f) dist = 0.1f; // where(sim==0, 0.1)
                float wgt = 1.f / dist;
                int lb = labL[bg];
#pragma unroll
                for (int c = 0; c < NCLS; c++) votes[c] += (lb == c) ? wgt : 0.f;
            }
        }
        __syncthreads();
    }
    if (tid == 0) {
        float bv = votes[0];
        int bc = 0;
#pragma unroll
        for (int c = 1; c < NCLS; c++)
            if (votes[c] > bv) { bv = votes[c]; bc = c; }
        out[q] = bc;
    }
}

extern "C" void kernel_launch(void* const* d_in, const int* in_sizes, int n_in,
                              void* d_out, int out_size, void* d_ws, size_t ws_size,
                              hipStream_t stream) {
    const float* Qm = (const float*)d_in[0];
    const float* X = (const float*)d_in[1];
    const int* labels = (const int*)d_in[2];
    char* ws = (char*)d_ws;
    // ws layout (total 26,236,416 B — R1 proved ws_size >= 34.6 MB):
    // [0,262144)          cnt_g  int[1024*64]
    // [262144,262148)     x2max  int
    // [262208,1062208)    x2     float[200000]
    // [1062208,1066304)   tqw    float[1024]
    // [1066304,1070400)   q2g    float[1024]
    // [1070592,26236416)  cand u32[1024*64*96]  ALIASED WITH keys u16[1024*8192]
    int* cnt_g = (int*)(ws + 0);
    int* x2max = (int*)(ws + 262144);
    float* x2 = (float*)(ws + 262208);
    float* tqw = (float*)(ws + 1062208);
    float* q2g = (float*)(ws + 1066304);
    unsigned short* keys = (unsigned short*)(ws + 1070592);
    unsigned* cand = (unsigned*)(ws + 1070592);
    int* out = (int*)d_out;

    hipMemsetAsync(ws, 0, 262148, stream);                 // cnt_g + x2max
    k_x2<<<12500, 256, 0, stream>>>(X, x2, x2max);
    k_gemm<1><<<64, 256, 0, stream>>>(X, Qm, x2, tqw, cnt_g, cand, keys);
    k_sel<<<NQ, 256, 0, stream>>>(keys, Qm, x2max, tqw, q2g);
    k_gemm<0><<<NQT * CHUNKS, 256, 0, stream>>>(X, Qm, x2, tqw, cnt_g, cand, keys);
    k_merge<<<NQ, 256, 0, stream>>>(Qm, X, x2, labels, cnt_g, cand, q2g, out);
}

// Round 4
// 578.244 us; speedup vs baseline: 4.7880x; 2.4347x over previous
//
#include <hip/hip_runtime.h>
#include <hip/hip_bf16.h>

#define N_TRAIN 200000
#define DIMS    64
#define NQ      1024
#define KSEL    32
#define NCLS    10

#define QB      128     // queries per gemm block (8 query tiles of 16)
#define NQT     8       // NQ/QB
#define CHUNKS  64      // n-chunks for filter
#define CHROWS  3125    // N_TRAIN / CHUNKS
#define CMAX    96      // candidate cap per (query, chunk)
#define MAXC    4096    // merge candidate cap per query
#define SAMPLES 8192    // threshold sample rows (rows 0..8191)
#define SCH     256     // sample rows per MODE1 block
#define NXB     12500   // k_x2 grid

typedef float f32x4 __attribute__((ext_vector_type(4)));
typedef short bf16x8 __attribute__((ext_vector_type(8)));

__device__ __forceinline__ unsigned fmap(float f) {
    unsigned u = __float_as_uint(f);
    return u ^ ((u >> 31) ? 0xFFFFFFFFu : 0x80000000u);
}
__device__ __forceinline__ float funmap(unsigned m) {
    unsigned u = m ^ ((m >> 31) ? 0x80000000u : 0xFFFFFFFFu);
    return __uint_as_float(u);
}
__device__ __forceinline__ unsigned short f2bf(float f) {   // RNE f32->bf16 bits
    unsigned u = __float_as_uint(f);
    unsigned r = u + 0x7FFFu + ((u >> 16) & 1u);
    return (unsigned short)(r >> 16);
}
__device__ __forceinline__ bf16x8 pack8(float4 a, float4 b) {
    bf16x8 r;
    r[0] = (short)f2bf(a.x); r[1] = (short)f2bf(a.y);
    r[2] = (short)f2bf(a.z); r[3] = (short)f2bf(a.w);
    r[4] = (short)f2bf(b.x); r[5] = (short)f2bf(b.y);
    r[6] = (short)f2bf(b.z); r[7] = (short)f2bf(b.w);
    return r;
}

// ---------------------------------- x2 = ||x||^2 ; per-block max (NO atomics)
__global__ __launch_bounds__(256) void k_x2(const float* __restrict__ X,
                                            float* __restrict__ x2,
                                            float* __restrict__ bmax) {
    int T = blockIdx.x * 256 + threadIdx.x;      // 16 threads per row
    int row = T >> 4;
    int l16 = T & 15;
    float4 v = ((const float4*)X)[(long)row * 16 + l16];
    float p = v.x * v.x + v.y * v.y + v.z * v.z + v.w * v.w;
    p += __shfl_xor(p, 1);
    p += __shfl_xor(p, 2);
    p += __shfl_xor(p, 4);
    p += __shfl_xor(p, 8);    // all lanes in 16-group hold the row sum
    if (l16 == 0) x2[row] = p;
    float m = p;
    m = fmaxf(m, __shfl_xor(m, 16));
    m = fmaxf(m, __shfl_xor(m, 32));
    __shared__ float wm[4];
    if ((threadIdx.x & 63) == 0) wm[threadIdx.x >> 6] = m;
    __syncthreads();
    if (threadIdx.x == 0)
        bmax[blockIdx.x] = fmaxf(fmaxf(wm[0], wm[1]), fmaxf(wm[2], wm[3]));
}

// ---------------------------------- reduce bmax -> single float (1 block)
__global__ __launch_bounds__(256) void k_max(const float* __restrict__ bmax,
                                             float* __restrict__ x2maxf) {
    float m = -1e30f;
    for (int i = threadIdx.x; i < NXB; i += 256) m = fmaxf(m, bmax[i]);
#pragma unroll
    for (int d = 1; d < 64; d <<= 1) m = fmaxf(m, __shfl_xor(m, d));
    __shared__ float wm[4];
    if ((threadIdx.x & 63) == 0) wm[threadIdx.x >> 6] = m;
    __syncthreads();
    if (threadIdx.x == 0)
        *x2maxf = fmaxf(fmaxf(wm[0], wm[1]), fmaxf(wm[2], wm[3]));
}

// ------------------------------------------------ MFMA distance pass
// MODE 0: filter full dataset against widened thresholds, append candidates
// MODE 1: write u16-mapped keys for sample rows [cb*SCH, cb*SCH+SCH)
template<int MODE>
__global__ __launch_bounds__(256, 2) void k_gemm(
    const float* __restrict__ Xf,
    const float* __restrict__ Qm, const float* __restrict__ x2,
    const float* __restrict__ tqw, int* __restrict__ cnt_g,
    unsigned* __restrict__ cand, unsigned short* __restrict__ keys) {
    int bid = blockIdx.x;
    int qt = bid & (NQT - 1);
    int cb = bid >> 3;
    int r0 = cb * (MODE ? SCH : CHROWS);
    int rcnt = MODE ? SCH : CHROWS;

    int tid = threadIdx.x;
    int lane = tid & 63;
    int w = tid >> 6;          // wave 0..3
    int lr = lane & 15;        // A-row / B-col within tile
    int lk = lane >> 4;        // k-quarter 0..3

    __shared__ short xs[256 * 64];   // 32 KB, 16B chunks XOR-swizzled by row&7
    __shared__ float x2s[256];
    __shared__ float tqh[QB];

    if (MODE == 0 && tid < QB) tqh[tid] = 0.5f * tqw[(qt << 7) + tid];
    __syncthreads();

    float htqmax[8];
    if (MODE == 0) {
#pragma unroll
        for (int qi = 0; qi < 8; qi++) {
            int b = (qi << 4) + (lk << 2);
            htqmax[qi] = fmaxf(fmaxf(tqh[b], tqh[b + 1]), fmaxf(tqh[b + 2], tqh[b + 3]));
        }
    }

    // A fragments: lane holds Q[qt*128+qi*16+lr][kh*32 + lk*8 + j], j=0..7
    bf16x8 afr[8][2];
#pragma unroll
    for (int qi = 0; qi < 8; qi++) {
        int qrow = (qt << 7) + (qi << 4) + lr;
        const float4* qp0 = (const float4*)(Qm + (long)qrow * 64 + lk * 8);
        const float4* qp1 = (const float4*)(Qm + (long)qrow * 64 + 32 + lk * 8);
        afr[qi][0] = pack8(qp0[0], qp0[1]);
        afr[qi][1] = pack8(qp1[0], qp1[1]);
    }

    for (int sb = 0; sb < rcnt; sb += 256) {
        int nv = min(256, rcnt - sb);
        __syncthreads();
#pragma unroll
        for (int m = 0; m < 8; m++) {
            int c = tid + 256 * m;              // 2048 16B chunks
            int row = c >> 3, ch = c & 7;
            bf16x8 v = {0, 0, 0, 0, 0, 0, 0, 0};
            if (row < nv) {
                long gr = (long)(r0 + sb + row);
                const float4* xp = (const float4*)(Xf + gr * 64 + ch * 8);
                v = pack8(xp[0], xp[1]);
            }
            *(bf16x8*)(xs + row * 64 + ((ch ^ (row & 7)) * 8)) = v;
        }
        x2s[tid] = (tid < nv) ? x2[r0 + sb + tid] : 1e30f;
        __syncthreads();

#pragma unroll
        for (int j = 0; j < 4; j++) {
            int nr = (w << 6) + (j << 4) + lr;   // local train row
            int sw = nr & 7;
            bf16x8 b0 = *(const bf16x8*)(xs + nr * 64 + ((lk ^ sw) * 8));
            bf16x8 b1 = *(const bf16x8*)(xs + nr * 64 + (((4 + lk) ^ sw) * 8));
            float x2v = x2s[nr];
            float hx = 0.5f * x2v;
#pragma unroll
            for (int qi = 0; qi < 8; qi++) {
                f32x4 acc = {0.f, 0.f, 0.f, 0.f};
                acc = __builtin_amdgcn_mfma_f32_16x16x32_bf16(afr[qi][0], b0, acc, 0, 0, 0);
                acc = __builtin_amdgcn_mfma_f32_16x16x32_bf16(afr[qi][1], b1, acc, 0, 0, 0);
                if (MODE == 1) {
                    int sg = r0 + sb + nr;
#pragma unroll
                    for (int r = 0; r < 4; r++) {
                        float key = x2v - 2.f * acc[r];
                        int qg = (qt << 7) + (qi << 4) + (lk << 2) + r;
                        keys[(long)qg * SAMPLES + sg] = (unsigned short)(fmap(key) >> 16);
                    }
                } else {
                    float mx = fmaxf(fmaxf(acc[0], acc[1]), fmaxf(acc[2], acc[3]));
                    if (mx + htqmax[qi] >= hx) {       // sound quick reject
#pragma unroll
                        for (int r = 0; r < 4; r++) {
                            if (acc[r] + tqh[(qi << 4) + (lk << 2) + r] >= hx) {
                                int qg = (qt << 7) + (qi << 4) + (lk << 2) + r;
                                int ng = r0 + sb + nr;
                                int slot = atomicAdd(&cnt_g[qg * CHUNKS + cb], 1);
                                if (slot < CMAX)
                                    cand[((long)qg * CHUNKS + cb) * CMAX + slot] = (unsigned)ng;
                            }
                        }
                    }
                }
            }
        }
    }
}

// ------------------------------------------------ 32nd-smallest sample key -> threshold
__global__ __launch_bounds__(256) void k_sel(const unsigned short* __restrict__ keys,
                                             const float* __restrict__ Qm,
                                             const float* __restrict__ x2maxf,
                                             float* __restrict__ tqw,
                                             float* __restrict__ q2g) {
    int q = blockIdx.x, tid = threadIdx.x;
    unsigned short mk[32];
#pragma unroll
    for (int m = 0; m < 32; m++) mk[m] = keys[(long)q * SAMPLES + tid + 256 * m];
    __shared__ float q2s_;
    __shared__ int cnt;
    if (tid < 64) {
        float v = Qm[(long)q * 64 + tid];
        float p = v * v;
#pragma unroll
        for (int d = 1; d < 64; d <<= 1) p += __shfl_xor(p, d);
        if (tid == 0) q2s_ = p;
    }
    unsigned lo = 0, hi = 65535;
    for (int it = 0; it < 16; ++it) {
        __syncthreads();
        if (tid == 0) cnt = 0;
        __syncthreads();
        unsigned mid = (lo + hi) >> 1;
        int c = 0;
#pragma unroll
        for (int m = 0; m < 32; m++) c += (mk[m] <= mid) ? 1 : 0;
#pragma unroll
        for (int d = 1; d < 64; d <<= 1) c += __shfl_xor(c, d);
        if ((tid & 63) == 0) atomicAdd(&cnt, c);
        __syncthreads();
        if (cnt >= KSEL) hi = mid; else lo = mid + 1;
    }
    if (tid == 0) {
        unsigned vv = hi + 2u; if (vv > 65535u) vv = 65535u;
        float t = funmap(vv << 16);
        float x2m = *x2maxf;
        float q2 = q2s_;
        // widen: 2 * bf16 dot-error bound (2^-6.99 * ||q|| * ||x||max each) + margin
        tqw[q] = t + 0.0314f * sqrtf(q2 * x2m) + 0.2f;
        q2g[q] = q2;
    }
}

// ------------------------------------------------ exact re-rank + vote + argmax
__global__ __launch_bounds__(256) void k_merge(const float* __restrict__ Qm,
                                               const float* __restrict__ X,
                                               const float* __restrict__ x2,
                                               const int* __restrict__ labels,
                                               const int* __restrict__ cnt_g,
                                               const unsigned* __restrict__ cand,
                                               const float* __restrict__ q2g,
                                               int* __restrict__ out) {
    int q = blockIdx.x, tid = threadIdx.x;
    __shared__ int idxL[MAXC];
    __shared__ float keyL[MAXC];
    __shared__ int labL[MAXC];
    __shared__ float qs[64];
    __shared__ int cnts[CHUNKS];
    __shared__ int tot, cnt, nw, nt;
    __shared__ float wKey[34];
    __shared__ int wLab[34];
    __shared__ int tIdx[64];
    __shared__ int tLab[64];

    if (tid == 0) { tot = 0; nw = 0; nt = 0; }
    if (tid < CHUNKS) cnts[tid] = min(cnt_g[q * CHUNKS + tid], CMAX);
    if (tid < 64) qs[tid] = Qm[(long)q * 64 + tid];
    for (int i = tid; i < MAXC; i += 256) { keyL[i] = 1e30f; idxL[i] = 0x7FFFFFFF; labL[i] = 0; }
    __syncthreads();

#pragma unroll
    for (int m = 0; m < 24; m++) {           // 64 chunks * 96 slots = 6144
        int g = tid + 256 * m;
        int c = g / CMAX, s = g - c * CMAX;
        if (s < cnts[c]) {
            int p = atomicAdd(&tot, 1);
            if (p < MAXC) idxL[p] = (int)cand[((long)q * CHUNKS + c) * CMAX + s];
        }
    }
    __syncthreads();
    int T = min(tot, MAXC);
    for (int i = tid; i < T; i += 256) {     // exact fp32 keys for candidates
        int ix = idxL[i];
        const float4* xr = (const float4*)(X + (long)ix * 64);
        const float4* qr = (const float4*)qs;
        float dot = 0.f;
#pragma unroll
        for (int k4 = 0; k4 < 16; k4++) {
            float4 xv = xr[k4];
            float4 qv = qr[k4];
            dot += qv.x * xv.x + qv.y * xv.y + qv.z * xv.z + qv.w * xv.w;
        }
        keyL[i] = x2[ix] - 2.f * dot;
        labL[i] = labels[ix];
    }
    __syncthreads();

    // register copy of mapped keys: exact 32nd-smallest via 32-step bisection
    unsigned uk[16];
#pragma unroll
    for (int m = 0; m < 16; m++) uk[m] = fmap(keyL[tid + 256 * m]);

    unsigned lo = 0u, hi = 0xFFFFFFFFu;
    for (int it = 0; it < 32; ++it) {
        __syncthreads();
        if (tid == 0) cnt = 0;
        __syncthreads();
        unsigned mid = lo + ((hi - lo) >> 1);
        int c = 0;
#pragma unroll
        for (int m = 0; m < 16; m++) c += (uk[m] <= mid) ? 1 : 0;
#pragma unroll
        for (int d = 1; d < 64; d <<= 1) c += __shfl_xor(c, d);
        if ((tid & 63) == 0) atomicAdd(&cnt, c);
        __syncthreads();
        if (cnt >= KSEL) hi = mid; else lo = mid + 1;
    }
    unsigned T32 = hi;   // count(<T32) <= 31, count(<=T32) >= 32

    // collect winners (key < T32) and boundary ties (key == T32)
#pragma unroll
    for (int m = 0; m < 16; m++) {
        int g = tid + 256 * m;
        if (uk[m] < T32) {
            int p = atomicAdd(&nw, 1);
            if (p < 34) { wKey[p] = keyL[g]; wLab[p] = labL[g]; }
        } else if (uk[m] == T32) {
            int p = atomicAdd(&nt, 1);
            if (p < 64) { tIdx[p] = idxL[g]; tLab[p] = labL[g]; }
        }
    }
    __syncthreads();

    if (tid == 0) {
        float q2v = q2g[q];
        float votes[NCLS] = {0.f, 0.f, 0.f, 0.f, 0.f, 0.f, 0.f, 0.f, 0.f, 0.f};
        int NW = min(nw, 32);
        for (int i = 0; i < NW; i++) {
            float dist = q2v + wKey[i];
            if (dist < 0.f) dist = 0.f;
            if (dist == 0.f) dist = 0.1f;
            votes[wLab[i]] += 1.f / dist;
        }
        // fill remaining slots from ties, smallest index first (top_k stability)
        int need = KSEL - NW;
        int NT = min(nt, 64);
        float tkey = funmap(T32);
        float dist = q2v + tkey;
        if (dist < 0.f) dist = 0.f;
        if (dist == 0.f) dist = 0.1f;
        float twgt = 1.f / dist;
        for (int t = 0; t < need && t < NT; t++) {
            int best = -1, bi = 0x7FFFFFFF;
            for (int u = 0; u < NT; u++)
                if (tIdx[u] < bi) { bi = tIdx[u]; best = u; }
            if (best < 0) break;
            votes[tLab[best]] += twgt;
            tIdx[best] = 0x7FFFFFFF;
        }
        float bv = votes[0];
        int bc = 0;
#pragma unroll
        for (int c = 1; c < NCLS; c++)
            if (votes[c] > bv) { bv = votes[c]; bc = c; }
        out[q] = bc;
    }
}

extern "C" void kernel_launch(void* const* d_in, const int* in_sizes, int n_in,
                              void* d_out, int out_size, void* d_ws, size_t ws_size,
                              hipStream_t stream) {
    const float* Qm = (const float*)d_in[0];
    const float* X = (const float*)d_in[1];
    const int* labels = (const int*)d_in[2];
    char* ws = (char*)d_ws;
    // ws layout (total ~26.3 MB; R1 proved ws_size >= 34.6 MB):
    // [0,262144)          cnt_g  int[1024*64]
    // [262144,1062144)    x2     float[200000]
    // [1062144,1066240)   tqw    float[1024]
    // [1066240,1070336)   q2g    float[1024]
    // [1070336,1070340)   x2maxf float
    // [1070400,1120400)   bmax   float[12500]
    // [1120512,26286336)  cand u32[1024*64*96]  ALIASED WITH keys u16[1024*8192]
    int* cnt_g = (int*)(ws + 0);
    float* x2 = (float*)(ws + 262144);
    float* tqw = (float*)(ws + 1062144);
    float* q2g = (float*)(ws + 1066240);
    float* x2maxf = (float*)(ws + 1070336);
    float* bmax = (float*)(ws + 1070400);
    unsigned short* keys = (unsigned short*)(ws + 1120512);
    unsigned* cand = (unsigned*)(ws + 1120512);
    int* out = (int*)d_out;

    hipMemsetAsync(cnt_g, 0, 262144, stream);
    k_x2<<<NXB, 256, 0, stream>>>(X, x2, bmax);
    k_max<<<1, 256, 0, stream>>>(bmax, x2maxf);
    k_gemm<1><<<NQT * (SAMPLES / SCH), 256, 0, stream>>>(X, Qm, x2, tqw, cnt_g, cand, keys);
    k_sel<<<NQ, 256, 0, stream>>>(keys, Qm, x2maxf, tqw, q2g);
    k_gemm<0><<<NQT * CHUNKS, 256, 0, stream>>>(X, Qm, x2, tqw, cnt_g, cand, keys);
    k_merge<<<NQ, 256, 0, stream>>>(Qm, X, x2, labels, cnt_g, cand, q2g, out);
}